// Round 4
// baseline (700.762 us; speedup 1.0000x reference)
//
#include <hip/hip_runtime.h>
#include <hip/hip_bf16.h>
#include <cstdint>

#define HD 64
#define NNODES 200000
#define NS_ELEMS (NNODES * HD)          // 12,800,000

typedef short bf8 __attribute__((ext_vector_type(8)));
typedef float f32x4 __attribute__((ext_vector_type(4)));

// ---- order-preserving float <-> uint for atomicMax ----
__device__ __forceinline__ unsigned enc_f32(float f) {
    unsigned u = __float_as_uint(f);
    return (u & 0x80000000u) ? ~u : (u | 0x80000000u);
}
__device__ __forceinline__ float dec_f32(unsigned v) {
    return (v & 0x80000000u) ? __uint_as_float(v & 0x7fffffffu)
                             : __uint_as_float(~v);
}

// RNE float -> bf16 bits, and back
__device__ __forceinline__ ushort f2bf(float f) {
    unsigned u = __float_as_uint(f);
    return (ushort)((u + 0x7fffu + ((u >> 16) & 1u)) >> 16);
}
__device__ __forceinline__ float bf2f(ushort b) {
    return __uint_as_float(((unsigned)b) << 16);
}

// ---- native packed 2x bf16 atomic add: guaranteed global_atomic_pk_add_bf16 ----
__device__ __forceinline__ void atom_pk(ushort* p, float lo, float hi) {
    __hip_bfloat162 v;
    v.x = __float2bfloat16(lo);
    v.y = __float2bfloat16(hi);
    (void)unsafeAtomicAdd((__hip_bfloat162*)p, v);
}

// ================= prep: ns fp32->bf16; weights fp32 -> bf16 frag-linear =====
struct PrepArgs {
    const float* src[8];
    ushort*      dst[8];
    int din[8], dout[8], nelem[8];
};

__global__ __launch_bounds__(256) void prep_kernel(
    const float* __restrict__ ns, ushort* __restrict__ ns16, PrepArgs pa, int total)
{
    int stride = gridDim.x * 256;
    for (int i = blockIdx.x * 256 + threadIdx.x; i < total; i += stride) {
        if (i < NS_ELEMS) { ns16[i] = f2bf(ns[i]); continue; }
        int e = i - NS_ELEMS;
        #pragma unroll
        for (int m = 0; m < 8; m++) {
            if (e < pa.nelem[m]) {
                int din = pa.din[m], dout = pa.dout[m];
                int n = e / din, k = e - n * din;
                pa.dst[m][(k >> 5) * dout * 32 + n * 32 + (k & 31)] = f2bf(pa.src[m][e]);
                e = 0x7fffffff;
            } else {
                e -= pa.nelem[m];
            }
        }
    }
}

// ================= MFMA layer helpers =======================================
template<int DIN, int DOUT, int NT>
__device__ __forceinline__ void load_bf(const ushort* __restrict__ WT,
                                        int wave, int lane, bf8 (&bf)[NT][DIN / 32])
{
    constexpr int KS = DIN / 32;
    const int q = lane >> 4, ln = lane & 15, n0 = wave * NT * 16;
    #pragma unroll
    for (int nt = 0; nt < NT; nt++)
        #pragma unroll
        for (int ks = 0; ks < KS; ks++)
            bf[nt][ks] = *(const bf8*)(WT + (size_t)ks * DOUT * 32
                                          + (n0 + nt * 16 + ln) * 32 + q * 8);
}

template<int DIN, int DOUT, int NT, int PDIN>
__device__ __forceinline__ void mfma_compute(const float* __restrict__ bias,
                                             const ushort* __restrict__ Xs,
                                             int wave, int lane,
                                             const bf8 (&bf)[NT][DIN / 32],
                                             f32x4 acc[2][NT])
{
    constexpr int KS = DIN / 32;
    const int q = lane >> 4, ln = lane & 15, n0 = wave * NT * 16;
    #pragma unroll
    for (int nt = 0; nt < NT; nt++) {
        float bv = bias[n0 + nt * 16 + ln];
        acc[0][nt] = f32x4{bv, bv, bv, bv};
        acc[1][nt] = f32x4{bv, bv, bv, bv};
    }
    #pragma unroll
    for (int mt = 0; mt < 2; mt++) {
        bf8 af[KS];
        #pragma unroll
        for (int ks = 0; ks < KS; ks++)
            af[ks] = *(const bf8*)(Xs + (mt * 16 + ln) * PDIN + ks * 32 + q * 8);
        #pragma unroll
        for (int ks = 0; ks < KS; ks++)
            #pragma unroll
            for (int nt = 0; nt < NT; nt++)
                acc[mt][nt] = __builtin_amdgcn_mfma_f32_16x16x32_bf16(
                    af[ks], bf[nt][ks], acc[mt][nt], 0, 0, 0);
    }
}

template<int DIN, int DOUT, int NT, int PDIN>
__device__ __forceinline__ void mfma_layer(
    const ushort* __restrict__ WT, const float* __restrict__ bias,
    const ushort* __restrict__ Xs, int wave, int lane, f32x4 acc[2][NT])
{
    bf8 bf[NT][DIN / 32];
    load_bf<DIN, DOUT, NT>(WT, wave, lane, bf);
    mfma_compute<DIN, DOUT, NT, PDIN>(bias, Xs, wave, lane, bf, acc);
}

// ================= relation kernel ==========================================
template<int A>
__global__ __launch_bounds__(256) void rel_mfma(
    const ushort* __restrict__ ns16, const int* __restrict__ idx,
    const ushort* __restrict__ wt1, const float* __restrict__ b1,
    const ushort* __restrict__ wt2, const float* __restrict__ b2,
    ushort* __restrict__ S16, unsigned* __restrict__ Mword)
{
    constexpr int D  = A * HD;
    constexpr int PD = D + 8;
    constexpr int NT = D / 64;
    constexpr int KS = D / 32;
    __shared__ __align__(16) ushort Xs[32 * PD];
    __shared__ __align__(16) ushort Hs[32 * PD];
    __shared__ int Is[32 * A];
    __shared__ float wred[4];

    const int tid = threadIdx.x;
    const int t0  = blockIdx.x * 32;
    const int wave = tid >> 6, lane = tid & 63;
    const int q = lane >> 4, ln = lane & 15, n0 = wave * NT * 16;

    f32x4 acc[2][NT];

    if constexpr (A == 2) {
        // hoist layer-1 B-frags ahead of the gather (independent of Xs)
        bf8 bf1[NT][KS];
        load_bf<D, D, NT>(wt1, wave, lane, bf1);

        if (tid < 32 * A) Is[tid] = idx[t0 * A + tid];
        for (int lin = tid; lin < 32 * A * 8; lin += 256) {
            int slot = lin >> 3, part = lin & 7;
            int node = idx[t0 * A + slot];
            int row = slot / A, sub = slot - row * A;
            *(uint4*)(Xs + row * PD + sub * 64 + part * 8) =
                *(const uint4*)(ns16 + (size_t)node * HD + part * 8);
        }
        __syncthreads();

        mfma_compute<D, D, NT, PD>(b1, Xs, wave, lane, bf1, acc);
        #pragma unroll
        for (int mt = 0; mt < 2; mt++)
            #pragma unroll
            for (int nt = 0; nt < NT; nt++)
                #pragma unroll
                for (int r = 0; r < 4; r++)
                    Hs[(mt * 16 + q * 4 + r) * PD + n0 + nt * 16 + ln] =
                        f2bf(fmaxf(acc[mt][nt][r], 0.f));
        // hoist layer-2 B-frags ahead of the barrier
        bf8 bf2[NT][KS];
        load_bf<D, D, NT>(wt2, wave, lane, bf2);
        __syncthreads();
        mfma_compute<D, D, NT, PD>(b2, Hs, wave, lane, bf2, acc);
    } else {
        if (tid < 32 * A) Is[tid] = idx[t0 * A + tid];
        for (int lin = tid; lin < 32 * A * 8; lin += 256) {
            int slot = lin >> 3, part = lin & 7;
            int node = idx[t0 * A + slot];
            int row = slot / A, sub = slot - row * A;
            *(uint4*)(Xs + row * PD + sub * 64 + part * 8) =
                *(const uint4*)(ns16 + (size_t)node * HD + part * 8);
        }
        __syncthreads();
        mfma_layer<D, D, NT, PD>(wt1, b1, Xs, wave, lane, acc);
        #pragma unroll
        for (int mt = 0; mt < 2; mt++)
            #pragma unroll
            for (int nt = 0; nt < NT; nt++)
                #pragma unroll
                for (int r = 0; r < 4; r++)
                    Hs[(mt * 16 + q * 4 + r) * PD + n0 + nt * 16 + ln] =
                        f2bf(fmaxf(acc[mt][nt][r], 0.f));
        __syncthreads();
        mfma_layer<D, D, NT, PD>(wt2, b2, Hs, wave, lane, acc);
    }

    // epilogue: native pk-bf16 scatter of exp(8*o); pair feats via lane^1 swap
    float m = -3.0e38f;
    const bool even = (ln & 1) == 0;
    #pragma unroll
    for (int mt = 0; mt < 2; mt++)
        #pragma unroll
        for (int nt = 0; nt < NT; nt++) {
            int colg = n0 + nt * 16 + ln;
            int sub  = colg >> 6;
            int featp = (colg & 63) & ~1;
            float e[4], p[4];
            #pragma unroll
            for (int r = 0; r < 4; r++) {
                float o = acc[mt][nt][r];
                m = fmaxf(m, o);
                e[r] = __expf(8.f * o);
            }
            #pragma unroll
            for (int r = 0; r < 4; r++) p[r] = __shfl_xor(e[r], 1);
            #pragma unroll
            for (int j = 0; j < 2; j++) {
                int r   = even ? j : (2 + j);
                int row = mt * 16 + q * 4 + r;
                int node = Is[row * A + sub];
                float lo = even ? e[r] : p[r];
                float hi = even ? p[r] : e[r];
                atom_pk(S16 + (size_t)node * HD + featp, lo, hi);
            }
        }
    #pragma unroll
    for (int off = 32; off; off >>= 1) m = fmaxf(m, __shfl_xor(m, off));
    if (lane == 0) wred[wave] = m;
    __syncthreads();
    if (tid == 0)
        atomicMax(Mword, enc_f32(fmaxf(fmaxf(wred[0], wred[1]),
                                       fmaxf(wred[2], wred[3]))));
}

// ================= update kernel ============================================
__global__ __launch_bounds__(256) void update_mfma(
    const ushort* __restrict__ ns16, const ushort* __restrict__ S16,
    const unsigned* __restrict__ Mword,
    const ushort* __restrict__ wt1, const float* __restrict__ b1,
    const ushort* __restrict__ wt2, const float* __restrict__ b2,
    float* __restrict__ out)
{
    constexpr int D = 128, PD = D + 8;
    __shared__ __align__(16) ushort Xs[32 * PD];
    __shared__ __align__(16) ushort Hs[32 * PD];

    const int tid = threadIdx.x;
    const int r0  = blockIdx.x * 32;
    const float corr = 1e-16f * __expf(8.f * dec_f32(*Mword));

    for (int lin = tid; lin < 32 * 16; lin += 256) {
        int row = lin >> 4, c8 = (lin & 15) * 8;
        if (c8 < 64) {
            ushort raw[8], tmp[8];
            *(uint4*)raw = *(const uint4*)(S16 + (size_t)(r0 + row) * HD + c8);
            #pragma unroll
            for (int j = 0; j < 8; j++)
                tmp[j] = f2bf(0.125f * __logf(bf2f(raw[j]) + corr));
            *(uint4*)(Xs + row * PD + c8) = *(uint4*)tmp;
        } else {
            *(uint4*)(Xs + row * PD + c8) =
                *(const uint4*)(ns16 + (size_t)(r0 + row) * HD + (c8 - 64));
        }
    }
    __syncthreads();

    const int wave = tid >> 6, lane = tid & 63;
    const int q = lane >> 4, ln = lane & 15;

    f32x4 acc[2][2];
    mfma_layer<128, 128, 2, PD>(wt1, b1, Xs, wave, lane, acc);
    #pragma unroll
    for (int mt = 0; mt < 2; mt++)
        #pragma unroll
        for (int nt = 0; nt < 2; nt++)
            #pragma unroll
            for (int r = 0; r < 4; r++)
                Hs[(mt * 16 + q * 4 + r) * PD + wave * 32 + nt * 16 + ln] =
                    f2bf(fmaxf(acc[mt][nt][r], 0.f));
    __syncthreads();

    f32x4 acc2[2][1];
    mfma_layer<128, 64, 1, PD>(wt2, b2, Hs, wave, lane, acc2);
    #pragma unroll
    for (int mt = 0; mt < 2; mt++)
        #pragma unroll
        for (int r = 0; r < 4; r++)
            out[(size_t)(r0 + mt * 16 + q * 4 + r) * HD + wave * 16 + ln] =
                acc2[mt][0][r];
}

// ================= host =====================================================
extern "C" void kernel_launch(void* const* d_in, const int* in_sizes, int n_in,
                              void* d_out, int out_size, void* d_ws, size_t ws_size,
                              hipStream_t stream)
{
    const float* ns   = (const float*)d_in[0];
    const int*   idx0 = (const int*)d_in[1];
    const int*   idx1 = (const int*)d_in[2];
    const int*   idx2 = (const int*)d_in[3];
    const float* W[8] = { (const float*)d_in[4],  (const float*)d_in[6],
                          (const float*)d_in[8],  (const float*)d_in[10],
                          (const float*)d_in[12], (const float*)d_in[14],
                          (const float*)d_in[16], (const float*)d_in[18] };
    const float* B[8] = { (const float*)d_in[5],  (const float*)d_in[7],
                          (const float*)d_in[9],  (const float*)d_in[11],
                          (const float*)d_in[13], (const float*)d_in[15],
                          (const float*)d_in[17], (const float*)d_in[19] };
    static const int DIN[8]  = {128,128,128,128,192,192,128,128};
    static const int DOUT[8] = {128,128,128,128,192,192,128, 64};

    // ws layout: S16 (bf16) | Mword | ns16 | weight frags
    ushort*   S16  = (ushort*)d_ws;
    size_t    offM = (size_t)NNODES * HD * sizeof(ushort);     // 25,600,000
    unsigned* Mw   = (unsigned*)((char*)d_ws + offM);
    ushort*   ns16 = (ushort*)((char*)d_ws + offM + 64);
    ushort*   WTb  = ns16 + (size_t)NS_ELEMS;

    PrepArgs pa;
    int total = NS_ELEMS;
    ushort* wt[8];
    {
        ushort* p = WTb;
        for (int m = 0; m < 8; m++) {
            pa.src[m] = W[m];
            pa.dst[m] = p;  wt[m] = p;
            pa.din[m] = DIN[m]; pa.dout[m] = DOUT[m];
            pa.nelem[m] = DIN[m] * DOUT[m];
            p += pa.nelem[m];
            total += pa.nelem[m];
        }
    }

    hipMemsetAsync(d_ws, 0, offM + 64, stream);
    prep_kernel<<<4096, 256, 0, stream>>>(ns, ns16, pa, total);

    const int T0 = in_sizes[1] / 2;   // 300000
    const int T1 = in_sizes[2] / 2;   // 300000
    const int T2 = in_sizes[3] / 3;   // 200000

    rel_mfma<2><<<T0 / 32, 256, 0, stream>>>(ns16, idx0, wt[0], B[0], wt[1], B[1], S16, Mw);
    rel_mfma<2><<<T1 / 32, 256, 0, stream>>>(ns16, idx1, wt[2], B[2], wt[3], B[3], S16, Mw);
    rel_mfma<3><<<T2 / 32, 256, 0, stream>>>(ns16, idx2, wt[4], B[4], wt[5], B[5], S16, Mw);
    update_mfma<<<NNODES / 32, 256, 0, stream>>>(ns16, S16, Mw, wt[6], B[6], wt[7], B[7],
                                                 (float*)d_out);
}